// Round 2
// baseline (3624.675 us; speedup 1.0000x reference)
//
#include <hip/hip_runtime.h>

typedef __bf16 bf16x8 __attribute__((ext_vector_type(8)));
typedef float  f32x4  __attribute__((ext_vector_type(4)));

#define Bn  512
#define TM1 63

__device__ __forceinline__ float fast_rcp(float x){ return __builtin_amdgcn_rcpf(x); }
__device__ __forceinline__ float fast_tanh(float x){
    float e = __expf(2.0f*x);
    return 1.0f - 2.0f*fast_rcp(e + 1.0f);
}
__device__ __forceinline__ float fast_sigmoid(float x){
    return fast_rcp(1.0f + __expf(-x));
}

// ---------------- setup kernels ----------------

__global__ __launch_bounds__(256) void k_prep_weights(
    const float* __restrict__ W1, const float* __restrict__ Whh_f,
    const float* __restrict__ b_ih, const float* __restrict__ b_hh,
    __bf16* __restrict__ Wdc, __bf16* __restrict__ W1x, __bf16* __restrict__ Whh,
    float* __restrict__ bsum)
{
    int i = blockIdx.x*256 + threadIdx.x;
    int n = gridDim.x*256;
    for (int idx = i; idx < 512*1024; idx += n) {
        int f = idx >> 10, k = idx & 1023;
        Wdc[idx] = (__bf16)W1[f*1536 + k];
    }
    for (int idx = i; idx < 512*512; idx += n) {
        int f = idx >> 9, k = idx & 511;
        W1x[idx] = (__bf16)W1[f*1536 + 1024 + k];
    }
    for (int idx = i; idx < 2048*512; idx += n) {
        Whh[idx] = (__bf16)Whh_f[idx];
    }
    for (int idx = i; idx < 2048; idx += n) {
        bsum[idx] = b_ih[idx] + b_hh[idx];
    }
}

__global__ __launch_bounds__(256) void k_conv_x(const float* __restrict__ X, __bf16* __restrict__ Xb, int n)
{
    int idx = (blockIdx.x*256 + threadIdx.x)*4;
    if (idx < n) {
        float4 v = *(const float4*)(X + idx);
        Xb[idx+0] = (__bf16)v.x; Xb[idx+1] = (__bf16)v.y;
        Xb[idx+2] = (__bf16)v.z; Xb[idx+3] = (__bf16)v.w;
    }
}

// XW[m,f] = sum_e Xbf[m,e]*W1x[f,e] + b1[f], M=32256, N=512, K=512, out bf16
__global__ __launch_bounds__(256) void k_gemm_xw(
    const __bf16* __restrict__ A, const __bf16* __restrict__ Bm,
    const float* __restrict__ bias, __bf16* __restrict__ C)
{
    // XCD-chunked bijective swizzle: 4032 blocks = 8 XCDs x 504.
    // Each XCD gets a contiguous band of row-tiles (A-sharing tiles stay on one XCD's L2).
    int orig = (blockIdx.x & 7)*504 + (blockIdx.x >> 3);
    int tm = orig >> 3, tn = orig & 7;
    int lane = threadIdx.x & 63, wave = threadIdx.x >> 6;
    int wr = wave >> 1, wc = wave & 1;
    int l15 = lane & 15, l4 = lane >> 4;
    int row_a = tm*64 + wr*32;
    int col_b = tn*64 + wc*32;
    f32x4 acc[2][2] = {};
    const __bf16* Ap = A + (size_t)(row_a + l15)*512 + l4*8;
    const __bf16* Bp = Bm + (size_t)(col_b + l15)*512 + l4*8;
    #pragma unroll 4
    for (int kc = 0; kc < 512; kc += 32) {
        bf16x8 a0 = *(const bf16x8*)(Ap + kc);
        bf16x8 a1 = *(const bf16x8*)(Ap + 16*512 + kc);
        bf16x8 b0 = *(const bf16x8*)(Bp + kc);
        bf16x8 b1 = *(const bf16x8*)(Bp + 16*512 + kc);
        acc[0][0] = __builtin_amdgcn_mfma_f32_16x16x32_bf16(a0,b0,acc[0][0],0,0,0);
        acc[0][1] = __builtin_amdgcn_mfma_f32_16x16x32_bf16(a0,b1,acc[0][1],0,0,0);
        acc[1][0] = __builtin_amdgcn_mfma_f32_16x16x32_bf16(a1,b0,acc[1][0],0,0,0);
        acc[1][1] = __builtin_amdgcn_mfma_f32_16x16x32_bf16(a1,b1,acc[1][1],0,0,0);
    }
    #pragma unroll
    for (int mi=0; mi<2; mi++)
    #pragma unroll
    for (int ni=0; ni<2; ni++) {
        int r0 = row_a + mi*16 + l4*4;
        int c0 = col_b + ni*16 + l15;
        float bv = bias[c0];
        #pragma unroll
        for (int r=0; r<4; r++)
            C[(size_t)(r0+r)*512 + c0] = (__bf16)(acc[mi][ni][r] + bv);
    }
}

// ---------------- per-step kernels ----------------

// 8 waves/block, each wave a 16x32 sub-tile of a 64x64 tile.
// blocks 0..63:   dcW [512 x 512]  = dc[512 x 1024k] @ Wdc[512n x 1024k]^T
// blocks 64..319: dWhh [512 x 2048] = d [512 x 512k]  @ Whh[2048n x 512k]^T
__global__ __launch_bounds__(512) void k_step_gemm(
    const __bf16* __restrict__ dc, const __bf16* __restrict__ Wdc,
    const __bf16* __restrict__ Whh, float* __restrict__ dcW, float* __restrict__ dWhh)
{
    int blk = blockIdx.x;
    const __bf16* Bm; float* C; int K, ldb, ldc, tm, tn;
    if (blk < 64) { tm = blk >> 3; tn = blk & 7;  Bm = Wdc; C = dcW;  K = 1024; ldb = 1024; ldc = 512; }
    else { int b2 = blk - 64; tm = b2 >> 5; tn = b2 & 31; Bm = Whh; C = dWhh; K = 512; ldb = 512; ldc = 2048; }

    int lane = threadIdx.x & 63, wave = threadIdx.x >> 6;
    int wr = wave >> 1, wc = wave & 1;     // wr 0..3, wc 0..1
    int l15 = lane & 15, l4 = lane >> 4;
    int row_a = tm*64 + wr*16;
    int col_b = tn*64 + wc*32;
    f32x4 acc0 = {}, acc1 = {};
    const __bf16* Ap = dc + (size_t)(row_a + l15)*1024 + l4*8;
    const __bf16* Bp = Bm + (size_t)(col_b + l15)*ldb + l4*8;
    #pragma unroll 4
    for (int kc = 0; kc < K; kc += 32) {
        bf16x8 a0 = *(const bf16x8*)(Ap + kc);
        bf16x8 b0 = *(const bf16x8*)(Bp + kc);
        bf16x8 b1 = *(const bf16x8*)(Bp + (size_t)16*ldb + kc);
        acc0 = __builtin_amdgcn_mfma_f32_16x16x32_bf16(a0,b0,acc0,0,0,0);
        acc1 = __builtin_amdgcn_mfma_f32_16x16x32_bf16(a0,b1,acc1,0,0,0);
    }
    int r0 = row_a + l4*4;
    int c0 = col_b + l15;
    #pragma unroll
    for (int r=0; r<4; r++) {
        C[(size_t)(r0+r)*ldc + c0]      = acc0[r];
        C[(size_t)(r0+r)*ldc + c0 + 16] = acc1[r];
    }
}

// one block (512 threads) per batch row
__global__ __launch_bounds__(512) void k_step_fused(
    int t,
    const float* __restrict__ dcW, const float* __restrict__ dWhh,
    const __bf16* __restrict__ XWb, const __bf16* __restrict__ Xbf,
    const float* __restrict__ y_prev, const float* __restrict__ W2,
    const float* __restrict__ fcW, const float* __restrict__ fcb,
    const float* __restrict__ W_ih, const float* __restrict__ bsum,
    float* __restrict__ c_f32, float* __restrict__ d_f32,
    __bf16* __restrict__ dc_bf16, float* __restrict__ ctx_last)
{
    int b = blockIdx.x;
    int tid = threadIdx.x, lane = tid & 63, wave = tid >> 6;
    __shared__ float s_dcw[512];
    __shared__ float s_w2[512];
    __shared__ float s_part[8][64];
    __shared__ float s_beta[64];
    __shared__ float s_ctx[8][512];
    __shared__ float s_red[8];
    __shared__ float s_y;

    s_dcw[tid] = dcW[(size_t)b*512 + tid];
    s_w2[tid]  = W2[tid];
    __syncthreads();

    // ---- scores: lane = t-slot, wave = f-chunk (64 f each) ----
    {
        float p = 0.f;
        if (lane < 63) {
            const __bf16* xwp = XWb + ((size_t)b*TM1 + lane)*512 + wave*64;
            #pragma unroll
            for (int j = 0; j < 8; ++j) {
                bf16x8 xw = *(const bf16x8*)(xwp + j*8);
                int f0 = wave*64 + j*8;
                #pragma unroll
                for (int i=0;i<8;i++)
                    p += s_w2[f0+i]*fast_tanh(s_dcw[f0+i] + (float)xw[i]);
            }
        }
        s_part[wave][lane] = p;
    }
    __syncthreads();
    // ---- softmax over 63 (wave 0) ----
    if (wave == 0) {
        float s = -1e30f;
        if (lane < 63) {
            s = 0.f;
            #pragma unroll
            for (int c2=0;c2<8;c2++) s += s_part[c2][lane];
        }
        float m = s;
        #pragma unroll
        for (int o=32;o;o>>=1) m = fmaxf(m, __shfl_xor(m,o,64));
        float e = (lane<63) ? __expf(s-m) : 0.f;
        float sum = e;
        #pragma unroll
        for (int o=32;o;o>>=1) sum += __shfl_xor(sum,o,64);
        s_beta[lane] = e*fast_rcp(sum);
    }
    __syncthreads();
    // ---- ctx: lane = e-chunk (8 e's), wave = t-group ----
    {
        float a8[8] = {0,0,0,0,0,0,0,0};
        const __bf16* xb = Xbf + (size_t)b*TM1*512 + lane*8;
        #pragma unroll
        for (int tt = wave; tt < TM1; tt += 8) {
            float bt = s_beta[tt];
            bf16x8 x = *(const bf16x8*)(xb + (size_t)tt*512);
            #pragma unroll
            for (int i=0;i<8;i++) a8[i] += bt*(float)x[i];
        }
        #pragma unroll
        for (int i=0;i<8;i++) s_ctx[wave][lane*8+i] = a8[i];
    }
    __syncthreads();
    float ctxv = 0.f;
    #pragma unroll
    for (int g=0; g<8; g++) ctxv += s_ctx[g][tid];
    if (t == 62) ctx_last[(size_t)b*512 + tid] = ctxv;
    // ---- y_tilde ----
    float part = fcW[tid]*ctxv;
    #pragma unroll
    for (int o=32;o;o>>=1) part += __shfl_xor(part,o,64);
    if (lane==0) s_red[wave] = part;
    __syncthreads();
    if (tid==0) {
        float y = 0.f;
        #pragma unroll
        for (int w2i=0;w2i<8;w2i++) y += s_red[w2i];
        y += fcW[512]*y_prev[(size_t)b*TM1 + t] + fcb[0];
        s_y = y;
    }
    __syncthreads();
    float yv = s_y;
    // ---- gates + state update: k = tid ----
    {
        int k = tid;
        size_t gb = (size_t)b*2048 + k;
        float gi = dWhh[gb]        + yv*W_ih[k]        + bsum[k];
        float gf = dWhh[gb+512]    + yv*W_ih[512+k]    + bsum[512+k];
        float gg = dWhh[gb+1024]   + yv*W_ih[1024+k]   + bsum[1024+k];
        float go = dWhh[gb+1536]   + yv*W_ih[1536+k]   + bsum[1536+k];
        size_t sk = (size_t)b*512 + k;
        float cn = fast_sigmoid(gf)*c_f32[sk] + fast_sigmoid(gi)*fast_tanh(gg);
        float dn = fast_sigmoid(go)*fast_tanh(cn);
        c_f32[sk] = cn; d_f32[sk] = dn;
        dc_bf16[(size_t)b*1024 + k]       = (__bf16)dn;
        dc_bf16[(size_t)b*1024 + 512 + k] = (__bf16)cn;
    }
}

// final heads: out[0:512]=beta, [512:1024]=sigma, [1024:1536]=gamma
__global__ __launch_bounds__(64) void k_heads(
    const float* __restrict__ d_f32, const float* __restrict__ ctx,
    const float* __restrict__ bW, const float* __restrict__ bb,
    const float* __restrict__ sW, const float* __restrict__ sb,
    const float* __restrict__ gW, const float* __restrict__ gb,
    float* __restrict__ out)
{
    int b = blockIdx.x, lane = threadIdx.x;
    float pb=0.f, ps=0.f, pg=0.f;
    for (int e = lane; e < 1024; e += 64) {
        float v = (e < 512) ? d_f32[(size_t)b*512 + e] : ctx[(size_t)b*512 + e - 512];
        pb += bW[e]*v; ps += sW[e]*v; pg += gW[e]*v;
    }
    #pragma unroll
    for (int o=32;o;o>>=1) {
        pb += __shfl_xor(pb,o,64); ps += __shfl_xor(ps,o,64); pg += __shfl_xor(pg,o,64);
    }
    if (lane==0) {
        out[b]        = pb + bb[0];
        out[512 + b]  = ps + sb[0];
        out[1024 + b] = pg + gb[0];
    }
}

extern "C" void kernel_launch(void* const* d_in, const int* in_sizes, int n_in,
                              void* d_out, int out_size, void* d_ws, size_t ws_size,
                              hipStream_t stream) {
    const float* X      = (const float*)d_in[0];
    const float* y_prev = (const float*)d_in[1];
    const float* W1     = (const float*)d_in[2];
    const float* b1     = (const float*)d_in[3];
    const float* W2     = (const float*)d_in[4];
    // d_in[5] = attn_b2 (softmax-invariant constant shift, skipped)
    const float* fcW    = (const float*)d_in[6];
    const float* fcb    = (const float*)d_in[7];
    const float* W_ih   = (const float*)d_in[8];
    const float* W_hh_f = (const float*)d_in[9];
    const float* b_ih   = (const float*)d_in[10];
    const float* b_hh   = (const float*)d_in[11];
    const float* betaW  = (const float*)d_in[12];
    const float* betab  = (const float*)d_in[13];
    const float* gammaW = (const float*)d_in[14];
    const float* gammab = (const float*)d_in[15];
    const float* sigmaW = (const float*)d_in[16];
    const float* sigmab = (const float*)d_in[17];
    float* out = (float*)d_out;

    size_t off = 0;
    char* ws = (char*)d_ws;
    auto alloc = [&](size_t bytes) { void* p = ws + off; off += (bytes + 255) & ~(size_t)255; return p; };
    __bf16* XWb  = (__bf16*)alloc((size_t)Bn*TM1*512*2);
    __bf16* Xbf  = (__bf16*)alloc((size_t)Bn*TM1*512*2);
    __bf16* Wdc  = (__bf16*)alloc((size_t)512*1024*2);
    __bf16* W1x  = (__bf16*)alloc((size_t)512*512*2);
    __bf16* Whh  = (__bf16*)alloc((size_t)2048*512*2);
    __bf16* dcb  = (__bf16*)alloc((size_t)Bn*1024*2);
    float*  cf   = (float*)alloc((size_t)Bn*512*4);
    float*  df   = (float*)alloc((size_t)Bn*512*4);
    float*  dcW  = (float*)alloc((size_t)Bn*512*4);
    float*  dWhh = (float*)alloc((size_t)Bn*2048*4);
    float*  ctxl = (float*)alloc((size_t)Bn*512*4);
    float*  bsum = (float*)alloc((size_t)2048*4);

    hipMemsetAsync(dcb, 0, (size_t)Bn*1024*2, stream);
    hipMemsetAsync(cf,  0, (size_t)Bn*512*4, stream);

    k_prep_weights<<<512, 256, 0, stream>>>(W1, W_hh_f, b_ih, b_hh, Wdc, W1x, Whh, bsum);
    int nx = Bn*TM1*512;
    k_conv_x<<<(nx/4 + 255)/256, 256, 0, stream>>>(X, Xbf, nx);
    k_gemm_xw<<<(Bn*TM1/64)*8, 256, 0, stream>>>(Xbf, W1x, b1, XWb);

    for (int t = 0; t < TM1; ++t) {
        k_step_gemm<<<320, 512, 0, stream>>>(dcb, Wdc, Whh, dcW, dWhh);
        k_step_fused<<<Bn, 512, 0, stream>>>(t, dcW, dWhh, XWb, Xbf, y_prev, W2,
                                             fcW, fcb, W_ih, bsum,
                                             cf, df, dcb, ctxl);
    }
    k_heads<<<Bn, 64, 0, stream>>>(df, ctxl, betaW, betab, sigmaW, sigmab, gammaW, gammab, out);
}

// Round 3
// 3209.294 us; speedup vs baseline: 1.1294x; 1.1294x over previous
//
#include <hip/hip_runtime.h>

typedef __bf16 bf16x8 __attribute__((ext_vector_type(8)));
typedef float  f32x4  __attribute__((ext_vector_type(4)));

#define Bn  512
#define TM1 63

__device__ __forceinline__ float fast_rcp(float x){ return __builtin_amdgcn_rcpf(x); }
__device__ __forceinline__ float fast_tanh(float x){
    float e = __expf(2.0f*x);
    return 1.0f - 2.0f*fast_rcp(e + 1.0f);
}
__device__ __forceinline__ float fast_sigmoid(float x){
    return fast_rcp(1.0f + __expf(-x));
}

// ---------------- setup kernels ----------------

__global__ __launch_bounds__(256) void k_prep_weights(
    const float* __restrict__ W1, const float* __restrict__ Whh_f,
    const float* __restrict__ b_ih, const float* __restrict__ b_hh,
    __bf16* __restrict__ Wdc, __bf16* __restrict__ W1x, __bf16* __restrict__ Whh,
    float* __restrict__ bsum)
{
    int i = blockIdx.x*256 + threadIdx.x;
    int n = gridDim.x*256;
    for (int idx = i; idx < 512*1024; idx += n) {
        int f = idx >> 10, k = idx & 1023;
        Wdc[idx] = (__bf16)W1[f*1536 + k];
    }
    for (int idx = i; idx < 512*512; idx += n) {
        int f = idx >> 9, k = idx & 511;
        W1x[idx] = (__bf16)W1[f*1536 + 1024 + k];
    }
    for (int idx = i; idx < 2048*512; idx += n) {
        Whh[idx] = (__bf16)Whh_f[idx];
    }
    for (int idx = i; idx < 2048; idx += n) {
        bsum[idx] = b_ih[idx] + b_hh[idx];
    }
}

__global__ __launch_bounds__(256) void k_conv_x(const float* __restrict__ X, __bf16* __restrict__ Xb, int n)
{
    int idx = (blockIdx.x*256 + threadIdx.x)*4;
    if (idx < n) {
        float4 v = *(const float4*)(X + idx);
        Xb[idx+0] = (__bf16)v.x; Xb[idx+1] = (__bf16)v.y;
        Xb[idx+2] = (__bf16)v.z; Xb[idx+3] = (__bf16)v.w;
    }
}

// Xt[b][e][tt] (tt padded to 64, col 63 = 0) from X[b][tt][e]
__global__ __launch_bounds__(512) void k_transpose_x(
    const float* __restrict__ X, __bf16* __restrict__ Xt)
{
    int b = blockIdx.x, e = threadIdx.x;
    const float* xp = X + (size_t)b*TM1*512 + e;
    __bf16* op = Xt + ((size_t)b*512 + e)*64;
    #pragma unroll
    for (int c = 0; c < 8; ++c) {
        bf16x8 v;
        #pragma unroll
        for (int j = 0; j < 8; ++j) {
            int tt = c*8 + j;
            v[j] = (tt < TM1) ? (__bf16)xp[(size_t)tt*512] : (__bf16)0.f;
        }
        *(bf16x8*)(op + c*8) = v;
    }
}

// XW[m,f] = sum_e Xbf[m,e]*W1x[f,e] + b1[f]; M=32256,N=512,K=512; 16x16/wave, high TLP
__global__ __launch_bounds__(512) void k_gemm_xw(
    const __bf16* __restrict__ A, const __bf16* __restrict__ Bm,
    const float* __restrict__ bias, __bf16* __restrict__ C)
{
    int tm = blockIdx.x >> 3, tn = blockIdx.x & 7;
    int lane = threadIdx.x & 63, wave = threadIdx.x >> 6;
    int wr = wave >> 2, wc = wave & 3;
    int l15 = lane & 15, l4 = lane >> 4;
    int row_a = tm*32 + wr*16;
    int col_b = tn*64 + wc*16;
    f32x4 acc = {};
    const __bf16* Ap = A + (size_t)(row_a + l15)*512 + l4*8;
    const __bf16* Bp = Bm + (size_t)(col_b + l15)*512 + l4*8;
    #pragma unroll 4
    for (int kc = 0; kc < 512; kc += 32) {
        bf16x8 a0 = *(const bf16x8*)(Ap + kc);
        bf16x8 b0 = *(const bf16x8*)(Bp + kc);
        acc = __builtin_amdgcn_mfma_f32_16x16x32_bf16(a0,b0,acc,0,0,0);
    }
    int r0 = row_a + l4*4;
    int c0 = col_b + l15;
    float bv = bias[c0];
    #pragma unroll
    for (int r=0; r<4; r++)
        C[(size_t)(r0+r)*512 + c0] = (__bf16)(acc[r] + bv);
}

// ---------------- per-step kernels ----------------

// 640 blocks x 512t; wave = 16x16 tile; block tile 32x64.
// blocks 0..127:   dcW [512x512]   = dc[512x1024k] @ Wdc[512n x 1024k]^T
// blocks 128..639: dWhh [512x2048] = d [512x512k]  @ Whh[2048n x 512k]^T
__global__ __launch_bounds__(512) void k_step_gemm(
    const __bf16* __restrict__ dc, const __bf16* __restrict__ Wdc,
    const __bf16* __restrict__ Whh, float* __restrict__ dcW, float* __restrict__ dWhh)
{
    int blk = blockIdx.x;
    const __bf16* Bm; float* C; int K, ldb, ldc, tm, tn;
    if (blk < 128) { tm = blk >> 3; tn = blk & 7;  Bm = Wdc; C = dcW;  K = 1024; ldb = 1024; ldc = 512; }
    else { int b2 = blk - 128; tm = b2 >> 5; tn = b2 & 31; Bm = Whh; C = dWhh; K = 512; ldb = 512; ldc = 2048; }

    int lane = threadIdx.x & 63, wave = threadIdx.x >> 6;
    int wr = wave >> 2, wc = wave & 3;
    int l15 = lane & 15, l4 = lane >> 4;
    int row_a = tm*32 + wr*16;
    int col_b = tn*64 + wc*16;
    f32x4 acc = {};
    const __bf16* Ap = dc + (size_t)(row_a + l15)*1024 + l4*8;
    const __bf16* Bp = Bm + (size_t)(col_b + l15)*ldb + l4*8;
    #pragma unroll 4
    for (int kc = 0; kc < K; kc += 32) {
        bf16x8 a0 = *(const bf16x8*)(Ap + kc);
        bf16x8 b0 = *(const bf16x8*)(Bp + kc);
        acc = __builtin_amdgcn_mfma_f32_16x16x32_bf16(a0,b0,acc,0,0,0);
    }
    int r0 = row_a + l4*4;
    int c0 = col_b + l15;
    #pragma unroll
    for (int r=0; r<4; r++)
        C[(size_t)(r0+r)*ldc + c0] = acc[r];
}

// one block (512 threads) per batch row
#define PSTR 76   // s_part row stride (floats): spreads banks, 16B aligned
__global__ __launch_bounds__(512) void k_step_fused(
    int t,
    const float* __restrict__ dcW, const float* __restrict__ dWhh,
    const __bf16* __restrict__ XWb, const __bf16* __restrict__ Xt,
    const float* __restrict__ y_prev, const float* __restrict__ W2,
    const float* __restrict__ fcW, const float* __restrict__ fcb,
    const float* __restrict__ W_ih, const float* __restrict__ bsum,
    float* __restrict__ c_f32, float* __restrict__ d_f32,
    __bf16* __restrict__ dc_bf16, float* __restrict__ ctx_last)
{
    int b = blockIdx.x;
    int tid = threadIdx.x, lane = tid & 63, wave = tid >> 6;
    __shared__ float s_part[64*PSTR];
    __shared__ float s_sc[64];
    __shared__ float s_beta[64];
    __shared__ float s_red[8];
    __shared__ float s_y;

    // hoist per-lane W2 / dcW slices into registers (same f-slice for all 8 t's)
    float w2r[8], dr[8];
    {
        const float4* w2p = (const float4*)(W2 + lane*8);
        const float4* dp  = (const float4*)(dcW + (size_t)b*512 + lane*8);
        float4 w0 = w2p[0], w1 = w2p[1], e0v = dp[0], e1v = dp[1];
        w2r[0]=w0.x; w2r[1]=w0.y; w2r[2]=w0.z; w2r[3]=w0.w;
        w2r[4]=w1.x; w2r[5]=w1.y; w2r[6]=w1.z; w2r[7]=w1.w;
        dr[0]=e0v.x; dr[1]=e0v.y; dr[2]=e0v.z; dr[3]=e0v.w;
        dr[4]=e1v.x; dr[5]=e1v.y; dr[6]=e1v.z; dr[7]=e1v.w;
    }
    // ---- scores: wave w -> t in {w*8..w*8+7}, lane = f-slice (coalesced 1KB/row) ----
    {
        const __bf16* xwp = XWb + ((size_t)b*TM1 + wave*8)*512 + lane*8;
        #pragma unroll
        for (int j = 0; j < 8; ++j) {
            int tt = wave*8 + j;
            float p = 0.f;
            if (tt < TM1) {
                bf16x8 xw = *(const bf16x8*)(xwp + (size_t)j*512);
                #pragma unroll
                for (int i=0;i<8;i++) p += w2r[i]*fast_tanh(dr[i] + (float)xw[i]);
            }
            s_part[tt*PSTR + lane] = p;
        }
    }
    __syncthreads();
    // ---- batched cross-lane reduce: thread -> (tt = tid>>3, g = tid&7) ----
    {
        int tt = tid >> 3, g = tid & 7;
        const float4* pp = (const float4*)(s_part + tt*PSTR + g*8);
        float4 u0 = pp[0], u1 = pp[1];
        float r = u0.x+u0.y+u0.z+u0.w + u1.x+u1.y+u1.z+u1.w;
        r += __shfl_xor(r, 1, 64);
        r += __shfl_xor(r, 2, 64);
        r += __shfl_xor(r, 4, 64);
        if (g == 0) s_sc[tt] = r;
    }
    __syncthreads();
    // ---- softmax over 63 (wave 0) ----
    if (wave == 0) {
        float s = (lane < TM1) ? s_sc[lane] : -1e30f;
        float m = s;
        #pragma unroll
        for (int o=32;o;o>>=1) m = fmaxf(m, __shfl_xor(m,o,64));
        float e = (lane < TM1) ? __expf(s-m) : 0.f;
        float sum = e;
        #pragma unroll
        for (int o=32;o;o>>=1) sum += __shfl_xor(sum,o,64);
        s_beta[lane] = e*fast_rcp(sum);   // lane 63 -> 0
    }
    __syncthreads();
    // ---- ctx: thread owns e = tid; 8 independent bf16x8 loads from Xt ----
    float ctxv = 0.f;
    {
        const __bf16* xp = Xt + ((size_t)b*512 + tid)*64;
        #pragma unroll
        for (int c = 0; c < 8; ++c) {
            bf16x8 x = *(const bf16x8*)(xp + c*8);
            #pragma unroll
            for (int j = 0; j < 8; ++j)
                ctxv += s_beta[c*8+j]*(float)x[j];
        }
    }
    if (t == 62) ctx_last[(size_t)b*512 + tid] = ctxv;
    // ---- y_tilde ----
    float part = fcW[tid]*ctxv;
    #pragma unroll
    for (int o=32;o;o>>=1) part += __shfl_xor(part,o,64);
    if (lane==0) s_red[wave] = part;
    __syncthreads();
    if (tid==0) {
        float y = 0.f;
        #pragma unroll
        for (int w2i=0;w2i<8;w2i++) y += s_red[w2i];
        y += fcW[512]*y_prev[(size_t)b*TM1 + t] + fcb[0];
        s_y = y;
    }
    __syncthreads();
    float yv = s_y;
    // ---- gates + state update: k = tid ----
    {
        int k = tid;
        size_t gb = (size_t)b*2048 + k;
        float gi = dWhh[gb]        + yv*W_ih[k]        + bsum[k];
        float gf = dWhh[gb+512]    + yv*W_ih[512+k]    + bsum[512+k];
        float gg = dWhh[gb+1024]   + yv*W_ih[1024+k]   + bsum[1024+k];
        float go = dWhh[gb+1536]   + yv*W_ih[1536+k]   + bsum[1536+k];
        size_t sk = (size_t)b*512 + k;
        float cn = fast_sigmoid(gf)*c_f32[sk] + fast_sigmoid(gi)*fast_tanh(gg);
        float dn = fast_sigmoid(go)*fast_tanh(cn);
        c_f32[sk] = cn; d_f32[sk] = dn;
        dc_bf16[(size_t)b*1024 + k]       = (__bf16)dn;
        dc_bf16[(size_t)b*1024 + 512 + k] = (__bf16)cn;
    }
}

// final heads: out[0:512]=beta, [512:1024]=sigma, [1024:1536]=gamma
__global__ __launch_bounds__(64) void k_heads(
    const float* __restrict__ d_f32, const float* __restrict__ ctx,
    const float* __restrict__ bW, const float* __restrict__ bb,
    const float* __restrict__ sW, const float* __restrict__ sb,
    const float* __restrict__ gW, const float* __restrict__ gb,
    float* __restrict__ out)
{
    int b = blockIdx.x, lane = threadIdx.x;
    float pb=0.f, ps=0.f, pg=0.f;
    for (int e = lane; e < 1024; e += 64) {
        float v = (e < 512) ? d_f32[(size_t)b*512 + e] : ctx[(size_t)b*512 + e - 512];
        pb += bW[e]*v; ps += sW[e]*v; pg += gW[e]*v;
    }
    #pragma unroll
    for (int o=32;o;o>>=1) {
        pb += __shfl_xor(pb,o,64); ps += __shfl_xor(ps,o,64); pg += __shfl_xor(pg,o,64);
    }
    if (lane==0) {
        out[b]        = pb + bb[0];
        out[512 + b]  = ps + sb[0];
        out[1024 + b] = pg + gb[0];
    }
}

extern "C" void kernel_launch(void* const* d_in, const int* in_sizes, int n_in,
                              void* d_out, int out_size, void* d_ws, size_t ws_size,
                              hipStream_t stream) {
    const float* X      = (const float*)d_in[0];
    const float* y_prev = (const float*)d_in[1];
    const float* W1     = (const float*)d_in[2];
    const float* b1     = (const float*)d_in[3];
    const float* W2     = (const float*)d_in[4];
    // d_in[5] = attn_b2 (softmax-invariant constant shift, skipped)
    const float* fcW    = (const float*)d_in[6];
    const float* fcb    = (const float*)d_in[7];
    const float* W_ih   = (const float*)d_in[8];
    const float* W_hh_f = (const float*)d_in[9];
    const float* b_ih   = (const float*)d_in[10];
    const float* b_hh   = (const float*)d_in[11];
    const float* betaW  = (const float*)d_in[12];
    const float* betab  = (const float*)d_in[13];
    const float* gammaW = (const float*)d_in[14];
    const float* gammab = (const float*)d_in[15];
    const float* sigmaW = (const float*)d_in[16];
    const float* sigmab = (const float*)d_in[17];
    float* out = (float*)d_out;

    size_t off = 0;
    char* ws = (char*)d_ws;
    auto alloc = [&](size_t bytes) { void* p = ws + off; off += (bytes + 255) & ~(size_t)255; return p; };
    __bf16* XWb  = (__bf16*)alloc((size_t)Bn*TM1*512*2);
    __bf16* Xbf  = (__bf16*)alloc((size_t)Bn*TM1*512*2);
    __bf16* Xt   = (__bf16*)alloc((size_t)Bn*512*64*2);
    __bf16* Wdc  = (__bf16*)alloc((size_t)512*1024*2);
    __bf16* W1x  = (__bf16*)alloc((size_t)512*512*2);
    __bf16* Whh  = (__bf16*)alloc((size_t)2048*512*2);
    __bf16* dcb  = (__bf16*)alloc((size_t)Bn*1024*2);
    float*  cf   = (float*)alloc((size_t)Bn*512*4);
    float*  df   = (float*)alloc((size_t)Bn*512*4);
    float*  dcW  = (float*)alloc((size_t)Bn*512*4);
    float*  dWhh = (float*)alloc((size_t)Bn*2048*4);
    float*  ctxl = (float*)alloc((size_t)Bn*512*4);
    float*  bsum = (float*)alloc((size_t)2048*4);

    hipMemsetAsync(dcb, 0, (size_t)Bn*1024*2, stream);
    hipMemsetAsync(cf,  0, (size_t)Bn*512*4, stream);

    k_prep_weights<<<512, 256, 0, stream>>>(W1, W_hh_f, b_ih, b_hh, Wdc, W1x, Whh, bsum);
    int nx = Bn*TM1*512;
    k_conv_x<<<(nx/4 + 255)/256, 256, 0, stream>>>(X, Xbf, nx);
    k_transpose_x<<<Bn, 512, 0, stream>>>(X, Xt);
    k_gemm_xw<<<(Bn*TM1/32)*8, 512, 0, stream>>>(Xbf, W1x, b1, XWb);

    for (int t = 0; t < TM1; ++t) {
        k_step_gemm<<<640, 512, 0, stream>>>(dcb, Wdc, Whh, dcW, dWhh);
        k_step_fused<<<Bn, 512, 0, stream>>>(t, dcW, dWhh, XWb, Xt, y_prev, W2,
                                             fcW, fcb, W_ih, bsum,
                                             cf, df, dcb, ctxl);
    }
    k_heads<<<Bn, 64, 0, stream>>>(df, ctxl, betaW, betab, sigmaW, sigmab, gammaW, gammab, out);
}

// Round 4
// 2673.830 us; speedup vs baseline: 1.3556x; 1.2003x over previous
//
#include <hip/hip_runtime.h>

typedef __bf16 bf16x8 __attribute__((ext_vector_type(8)));
typedef float  f32x4  __attribute__((ext_vector_type(4)));

#define Bn  512
#define TM1 63

__device__ __forceinline__ float fast_rcp(float x){ return __builtin_amdgcn_rcpf(x); }
__device__ __forceinline__ float fast_tanh(float x){
    float e = __expf(2.0f*x);
    return 1.0f - 2.0f*fast_rcp(e + 1.0f);
}
__device__ __forceinline__ float fast_sigmoid(float x){
    return fast_rcp(1.0f + __expf(-x));
}

// ---------------- setup kernels ----------------

__global__ __launch_bounds__(256) void k_prep_weights(
    const float* __restrict__ W1, const float* __restrict__ Whh_f,
    const float* __restrict__ b_ih, const float* __restrict__ b_hh,
    __bf16* __restrict__ Wdc, __bf16* __restrict__ W1x, __bf16* __restrict__ Whh,
    float* __restrict__ bsum)
{
    int i = blockIdx.x*256 + threadIdx.x;
    int n = gridDim.x*256;
    for (int idx = i; idx < 512*1024; idx += n) {
        int f = idx >> 10, k = idx & 1023;
        Wdc[idx] = (__bf16)W1[f*1536 + k];
    }
    for (int idx = i; idx < 512*512; idx += n) {
        int f = idx >> 9, k = idx & 511;
        W1x[idx] = (__bf16)W1[f*1536 + 1024 + k];
    }
    for (int idx = i; idx < 2048*512; idx += n) {
        Whh[idx] = (__bf16)Whh_f[idx];
    }
    for (int idx = i; idx < 2048; idx += n) {
        bsum[idx] = b_ih[idx] + b_hh[idx];
    }
}

__global__ __launch_bounds__(256) void k_conv_x(const float* __restrict__ X, __bf16* __restrict__ Xb, int n)
{
    int idx = (blockIdx.x*256 + threadIdx.x)*4;
    if (idx < n) {
        float4 v = *(const float4*)(X + idx);
        Xb[idx+0] = (__bf16)v.x; Xb[idx+1] = (__bf16)v.y;
        Xb[idx+2] = (__bf16)v.z; Xb[idx+3] = (__bf16)v.w;
    }
}

// Xt[b][e][tt] (tt padded to 64, col 63 = 0) from X[b][tt][e]
__global__ __launch_bounds__(512) void k_transpose_x(
    const float* __restrict__ X, __bf16* __restrict__ Xt)
{
    int b = blockIdx.x, e = threadIdx.x;
    const float* xp = X + (size_t)b*TM1*512 + e;
    __bf16* op = Xt + ((size_t)b*512 + e)*64;
    #pragma unroll
    for (int c = 0; c < 8; ++c) {
        bf16x8 v;
        #pragma unroll
        for (int j = 0; j < 8; ++j) {
            int tt = c*8 + j;
            v[j] = (tt < TM1) ? (__bf16)xp[(size_t)tt*512] : (__bf16)0.f;
        }
        *(bf16x8*)(op + c*8) = v;
    }
}

// Shared 64x64-tile, 32x32/wave, register-double-buffered K-loop GEMM body.
// C[row,col] = sum_k A[row,k]*B[col,k]  (B row-major over its own rows)
template <int ADDBIAS>
__device__ __forceinline__ void gemm_tile_body(
    const __bf16* __restrict__ A, const __bf16* __restrict__ Bm,
    const float* __restrict__ bias, void* __restrict__ C, int as_bf16,
    int row0, int col0, int K, int lda, int ldb, int ldc)
{
    int lane = threadIdx.x & 63, wave = threadIdx.x >> 6;
    int wr = wave >> 1, wc = wave & 1;
    int l15 = lane & 15, l4 = lane >> 4;
    int row_a = row0 + wr*32;
    int col_b = col0 + wc*32;
    f32x4 acc00 = {}, acc01 = {}, acc10 = {}, acc11 = {};
    const __bf16* Ap = A + (size_t)(row_a + l15)*lda + l4*8;
    const __bf16* Bp = Bm + (size_t)(col_b + l15)*ldb + l4*8;
    const __bf16* Ap2 = Ap + (size_t)16*lda;
    const __bf16* Bp2 = Bp + (size_t)16*ldb;

    bf16x8 a0 = *(const bf16x8*)(Ap);
    bf16x8 a1 = *(const bf16x8*)(Ap2);
    bf16x8 b0 = *(const bf16x8*)(Bp);
    bf16x8 b1 = *(const bf16x8*)(Bp2);
    #pragma unroll 4
    for (int kc = 32; kc < K; kc += 32) {
        bf16x8 na0 = *(const bf16x8*)(Ap + kc);
        bf16x8 na1 = *(const bf16x8*)(Ap2 + kc);
        bf16x8 nb0 = *(const bf16x8*)(Bp + kc);
        bf16x8 nb1 = *(const bf16x8*)(Bp2 + kc);
        acc00 = __builtin_amdgcn_mfma_f32_16x16x32_bf16(a0,b0,acc00,0,0,0);
        acc01 = __builtin_amdgcn_mfma_f32_16x16x32_bf16(a0,b1,acc01,0,0,0);
        acc10 = __builtin_amdgcn_mfma_f32_16x16x32_bf16(a1,b0,acc10,0,0,0);
        acc11 = __builtin_amdgcn_mfma_f32_16x16x32_bf16(a1,b1,acc11,0,0,0);
        a0 = na0; a1 = na1; b0 = nb0; b1 = nb1;
    }
    acc00 = __builtin_amdgcn_mfma_f32_16x16x32_bf16(a0,b0,acc00,0,0,0);
    acc01 = __builtin_amdgcn_mfma_f32_16x16x32_bf16(a0,b1,acc01,0,0,0);
    acc10 = __builtin_amdgcn_mfma_f32_16x16x32_bf16(a1,b0,acc10,0,0,0);
    acc11 = __builtin_amdgcn_mfma_f32_16x16x32_bf16(a1,b1,acc11,0,0,0);

    f32x4 accs[2][2] = {{acc00, acc01}, {acc10, acc11}};
    #pragma unroll
    for (int mi=0; mi<2; mi++)
    #pragma unroll
    for (int ni=0; ni<2; ni++) {
        int r0 = row_a + mi*16 + l4*4;
        int c0 = col_b + ni*16 + l15;
        float bv = ADDBIAS ? bias[c0] : 0.f;
        if (as_bf16) {
            __bf16* Cb = (__bf16*)C;
            #pragma unroll
            for (int r=0; r<4; r++)
                Cb[(size_t)(r0+r)*ldc + c0] = (__bf16)(accs[mi][ni][r] + bv);
        } else {
            float* Cf = (float*)C;
            #pragma unroll
            for (int r=0; r<4; r++)
                Cf[(size_t)(r0+r)*ldc + c0] = accs[mi][ni][r];
        }
    }
}

// XW[m,f] = sum_e Xbf[m,e]*W1x[f,e] + b1[f]; M=32256,N=512,K=512
__global__ __launch_bounds__(256, 2) void k_gemm_xw(
    const __bf16* __restrict__ A, const __bf16* __restrict__ Bm,
    const float* __restrict__ bias, __bf16* __restrict__ C)
{
    // XCD-chunked bijective swizzle: 4032 blocks = 8 XCDs x 504
    int orig = (blockIdx.x & 7)*504 + (blockIdx.x >> 3);
    int tm = orig >> 3, tn = orig & 7;
    gemm_tile_body<1>(A, Bm, bias, C, 1, tm*64, tn*64, 512, 512, 512, 512);
}

// blocks 0..63:   dcW [512x512]   = dc[512x1024k] @ Wdc[512n x 1024k]^T
// blocks 64..319: dWhh [512x2048] = d [512x512k]  @ Whh[2048n x 512k]^T  (d = dc rows, lda=1024)
__global__ __launch_bounds__(256, 2) void k_step_gemm(
    const __bf16* __restrict__ dc, const __bf16* __restrict__ Wdc,
    const __bf16* __restrict__ Whh, float* __restrict__ dcW, float* __restrict__ dWhh)
{
    int blk = blockIdx.x;
    if (blk < 64) {
        int tm = blk >> 3, tn = blk & 7;
        gemm_tile_body<0>(dc, Wdc, nullptr, dcW, 0, tm*64, tn*64, 1024, 1024, 1024, 512);
    } else {
        int b2 = blk - 64;
        int tm = b2 >> 5, tn = b2 & 31;
        gemm_tile_body<0>(dc, Whh, nullptr, dWhh, 0, tm*64, tn*64, 512, 1024, 512, 2048);
    }
}

// ---------------- per-step fused kernel ----------------

// one block (512 threads) per batch row
#define PSTR 76   // s_part row stride (floats)
__global__ __launch_bounds__(512) void k_step_fused(
    int t,
    const float* __restrict__ dcW, const float* __restrict__ dWhh,
    const __bf16* __restrict__ XWb, const __bf16* __restrict__ Xt,
    const float* __restrict__ y_prev, const float* __restrict__ W2,
    const float* __restrict__ fcW, const float* __restrict__ fcb,
    const float* __restrict__ W_ih, const float* __restrict__ bsum,
    float* __restrict__ c_f32, float* __restrict__ d_f32,
    __bf16* __restrict__ dc_bf16, float* __restrict__ ctx_last)
{
    int b = blockIdx.x;
    int tid = threadIdx.x, lane = tid & 63, wave = tid >> 6;
    __shared__ float s_part[64*PSTR];
    __shared__ float s_sc[64];
    __shared__ float s_beta[64];
    __shared__ float s_red[8];
    __shared__ float s_y;

    // hoist per-lane W2 / dcW slices into registers (same f-slice for all 8 t's)
    float w2r[8], dr[8];
    {
        const float4* w2p = (const float4*)(W2 + lane*8);
        const float4* dp  = (const float4*)(dcW + (size_t)b*512 + lane*8);
        float4 w0 = w2p[0], w1 = w2p[1], e0v = dp[0], e1v = dp[1];
        w2r[0]=w0.x; w2r[1]=w0.y; w2r[2]=w0.z; w2r[3]=w0.w;
        w2r[4]=w1.x; w2r[5]=w1.y; w2r[6]=w1.z; w2r[7]=w1.w;
        dr[0]=e0v.x; dr[1]=e0v.y; dr[2]=e0v.z; dr[3]=e0v.w;
        dr[4]=e1v.x; dr[5]=e1v.y; dr[6]=e1v.z; dr[7]=e1v.w;
    }
    // ---- scores: wave w -> t in {w*8..w*8+7}, lane = f-slice (coalesced 1KB/row) ----
    {
        const __bf16* xwp = XWb + ((size_t)b*TM1 + wave*8)*512 + lane*8;
        #pragma unroll
        for (int j = 0; j < 8; ++j) {
            int tt = wave*8 + j;
            float p = 0.f;
            if (tt < TM1) {
                bf16x8 xw = *(const bf16x8*)(xwp + (size_t)j*512);
                #pragma unroll
                for (int i=0;i<8;i++) p += w2r[i]*fast_tanh(dr[i] + (float)xw[i]);
            }
            s_part[tt*PSTR + lane] = p;
        }
    }
    __syncthreads();
    // ---- batched cross-lane reduce: thread -> (tt = tid>>3, g = tid&7) ----
    {
        int tt = tid >> 3, g = tid & 7;
        const float4* pp = (const float4*)(s_part + tt*PSTR + g*8);
        float4 u0 = pp[0], u1 = pp[1];
        float r = u0.x+u0.y+u0.z+u0.w + u1.x+u1.y+u1.z+u1.w;
        r += __shfl_xor(r, 1, 64);
        r += __shfl_xor(r, 2, 64);
        r += __shfl_xor(r, 4, 64);
        if (g == 0) s_sc[tt] = r;
    }
    __syncthreads();
    // ---- softmax over 63 (wave 0); scores bounded by sum|W2| ~ 19 -> exp safe, no max pass
    if (wave == 0) {
        float e = (lane < TM1) ? __expf(s_sc[lane]) : 0.f;
        float sum = e;
        #pragma unroll
        for (int o=32;o;o>>=1) sum += __shfl_xor(sum,o,64);
        s_beta[lane] = e*fast_rcp(sum);   // lane 63 -> 0
    }
    __syncthreads();
    // ---- ctx: thread owns e = tid; 8 independent bf16x8 loads from Xt ----
    float ctxv = 0.f;
    {
        const __bf16* xp = Xt + ((size_t)b*512 + tid)*64;
        #pragma unroll
        for (int c = 0; c < 8; ++c) {
            bf16x8 x = *(const bf16x8*)(xp + c*8);
            #pragma unroll
            for (int j = 0; j < 8; ++j)
                ctxv += s_beta[c*8+j]*(float)x[j];
        }
    }
    if (t == 62) ctx_last[(size_t)b*512 + tid] = ctxv;
    // ---- y_tilde ----
    float part = fcW[tid]*ctxv;
    #pragma unroll
    for (int o=32;o;o>>=1) part += __shfl_xor(part,o,64);
    if (lane==0) s_red[wave] = part;
    __syncthreads();
    if (tid==0) {
        float y = 0.f;
        #pragma unroll
        for (int w2i=0;w2i<8;w2i++) y += s_red[w2i];
        y += fcW[512]*y_prev[(size_t)b*TM1 + t] + fcb[0];
        s_y = y;
    }
    __syncthreads();
    float yv = s_y;
    // ---- gates + state update: k = tid ----
    {
        int k = tid;
        size_t gb = (size_t)b*2048 + k;
        float gi = dWhh[gb]        + yv*W_ih[k]        + bsum[k];
        float gf = dWhh[gb+512]    + yv*W_ih[512+k]    + bsum[512+k];
        float gg = dWhh[gb+1024]   + yv*W_ih[1024+k]   + bsum[1024+k];
        float go = dWhh[gb+1536]   + yv*W_ih[1536+k]   + bsum[1536+k];
        size_t sk = (size_t)b*512 + k;
        float cn = fast_sigmoid(gf)*c_f32[sk] + fast_sigmoid(gi)*fast_tanh(gg);
        float dn = fast_sigmoid(go)*fast_tanh(cn);
        c_f32[sk] = cn; d_f32[sk] = dn;
        dc_bf16[(size_t)b*1024 + k]       = (__bf16)dn;
        dc_bf16[(size_t)b*1024 + 512 + k] = (__bf16)cn;
    }
}

// final heads: out[0:512]=beta, [512:1024]=sigma, [1024:1536]=gamma
__global__ __launch_bounds__(64) void k_heads(
    const float* __restrict__ d_f32, const float* __restrict__ ctx,
    const float* __restrict__ bW, const float* __restrict__ bb,
    const float* __restrict__ sW, const float* __restrict__ sb,
    const float* __restrict__ gW, const float* __restrict__ gb,
    float* __restrict__ out)
{
    int b = blockIdx.x, lane = threadIdx.x;
    float pb=0.f, ps=0.f, pg=0.f;
    for (int e = lane; e < 1024; e += 64) {
        float v = (e < 512) ? d_f32[(size_t)b*512 + e] : ctx[(size_t)b*512 + e - 512];
        pb += bW[e]*v; ps += sW[e]*v; pg += gW[e]*v;
    }
    #pragma unroll
    for (int o=32;o;o>>=1) {
        pb += __shfl_xor(pb,o,64); ps += __shfl_xor(ps,o,64); pg += __shfl_xor(pg,o,64);
    }
    if (lane==0) {
        out[b]        = pb + bb[0];
        out[512 + b]  = ps + sb[0];
        out[1024 + b] = pg + gb[0];
    }
}

extern "C" void kernel_launch(void* const* d_in, const int* in_sizes, int n_in,
                              void* d_out, int out_size, void* d_ws, size_t ws_size,
                              hipStream_t stream) {
    const float* X      = (const float*)d_in[0];
    const float* y_prev = (const float*)d_in[1];
    const float* W1     = (const float*)d_in[2];
    const float* b1     = (const float*)d_in[3];
    const float* W2     = (const float*)d_in[4];
    // d_in[5] = attn_b2 (softmax-invariant constant shift, skipped)
    const float* fcW    = (const float*)d_in[6];
    const float* fcb    = (const float*)d_in[7];
    const float* W_ih   = (const float*)d_in[8];
    const float* W_hh_f = (const float*)d_in[9];
    const float* b_ih   = (const float*)d_in[10];
    const float* b_hh   = (const float*)d_in[11];
    const float* betaW  = (const float*)d_in[12];
    const float* betab  = (const float*)d_in[13];
    const float* gammaW = (const float*)d_in[14];
    const float* gammab = (const float*)d_in[15];
    const float* sigmaW = (const float*)d_in[16];
    const float* sigmab = (const float*)d_in[17];
    float* out = (float*)d_out;

    size_t off = 0;
    char* ws = (char*)d_ws;
    auto alloc = [&](size_t bytes) { void* p = ws + off; off += (bytes + 255) & ~(size_t)255; return p; };
    __bf16* XWb  = (__bf16*)alloc((size_t)Bn*TM1*512*2);
    __bf16* Xbf  = (__bf16*)alloc((size_t)Bn*TM1*512*2);
    __bf16* Xt   = (__bf16*)alloc((size_t)Bn*512*64*2);
    __bf16* Wdc  = (__bf16*)alloc((size_t)512*1024*2);
    __bf16* W1x  = (__bf16*)alloc((size_t)512*512*2);
    __bf16* Whh  = (__bf16*)alloc((size_t)2048*512*2);
    __bf16* dcb  = (__bf16*)alloc((size_t)Bn*1024*2);
    float*  cf   = (float*)alloc((size_t)Bn*512*4);
    float*  df   = (float*)alloc((size_t)Bn*512*4);
    float*  dcW  = (float*)alloc((size_t)Bn*512*4);
    float*  dWhh = (float*)alloc((size_t)Bn*2048*4);
    float*  ctxl = (float*)alloc((size_t)Bn*512*4);
    float*  bsum = (float*)alloc((size_t)2048*4);

    hipMemsetAsync(dcb, 0, (size_t)Bn*1024*2, stream);
    hipMemsetAsync(cf,  0, (size_t)Bn*512*4, stream);

    k_prep_weights<<<512, 256, 0, stream>>>(W1, W_hh_f, b_ih, b_hh, Wdc, W1x, Whh, bsum);
    int nx = Bn*TM1*512;
    k_conv_x<<<(nx/4 + 255)/256, 256, 0, stream>>>(X, Xbf, nx);
    k_transpose_x<<<Bn, 512, 0, stream>>>(X, Xt);
    k_gemm_xw<<<(Bn*TM1/64)*8, 256, 0, stream>>>(Xbf, W1x, b1, XWb);

    for (int t = 0; t < TM1; ++t) {
        k_step_gemm<<<320, 256, 0, stream>>>(dcb, Wdc, Whh, dcW, dWhh);
        k_step_fused<<<Bn, 512, 0, stream>>>(t, dcW, dWhh, XWb, Xt, y_prev, W2,
                                             fcW, fcb, W_ih, bsum,
                                             cf, df, dcb, ctxl);
    }
    k_heads<<<Bn, 64, 0, stream>>>(df, ctxl, betaW, betab, sigmaW, sigmab, gammaW, gammab, out);
}

// Round 5
// 2010.613 us; speedup vs baseline: 1.8028x; 1.3299x over previous
//
#include <hip/hip_runtime.h>

typedef __bf16 bf16x8 __attribute__((ext_vector_type(8)));
typedef float  f32x4  __attribute__((ext_vector_type(4)));

#define Bn  512
#define TM1 63

__device__ __forceinline__ float fast_rcp(float x){ return __builtin_amdgcn_rcpf(x); }
__device__ __forceinline__ float fast_tanh(float x){
    float e = __expf(2.0f*x);
    return 1.0f - 2.0f*fast_rcp(e + 1.0f);
}
__device__ __forceinline__ float fast_sigmoid(float x){
    return fast_rcp(1.0f + __expf(-x));
}

// async global->LDS, 16B per lane; lds ptr must be wave-uniform (HW adds lane*16)
__device__ __forceinline__ void gll16(const __bf16* g, __bf16* l) {
    __builtin_amdgcn_global_load_lds(
        (const __attribute__((address_space(1))) unsigned int*)(g),
        (__attribute__((address_space(3))) unsigned int*)(l),
        16, 0, 0);
}

// ---------------- setup kernels ----------------

__global__ __launch_bounds__(256) void k_prep_weights(
    const float* __restrict__ W1, const float* __restrict__ Whh_f,
    const float* __restrict__ b_ih, const float* __restrict__ b_hh,
    __bf16* __restrict__ Wdc, __bf16* __restrict__ W1x, __bf16* __restrict__ Whh,
    float* __restrict__ bsum)
{
    int i = blockIdx.x*256 + threadIdx.x;
    int n = gridDim.x*256;
    for (int idx = i; idx < 512*1024; idx += n) {
        int f = idx >> 10, k = idx & 1023;
        Wdc[idx] = (__bf16)W1[f*1536 + k];
    }
    for (int idx = i; idx < 512*512; idx += n) {
        int f = idx >> 9, k = idx & 511;
        W1x[idx] = (__bf16)W1[f*1536 + 1024 + k];
    }
    for (int idx = i; idx < 2048*512; idx += n) {
        Whh[idx] = (__bf16)Whh_f[idx];
    }
    for (int idx = i; idx < 2048; idx += n) {
        bsum[idx] = b_ih[idx] + b_hh[idx];
    }
}

__global__ __launch_bounds__(256) void k_conv_x(const float* __restrict__ X, __bf16* __restrict__ Xb, int n)
{
    int idx = (blockIdx.x*256 + threadIdx.x)*4;
    if (idx < n) {
        float4 v = *(const float4*)(X + idx);
        Xb[idx+0] = (__bf16)v.x; Xb[idx+1] = (__bf16)v.y;
        Xb[idx+2] = (__bf16)v.z; Xb[idx+3] = (__bf16)v.w;
    }
}

// ---------------- LDS-staged 64x64-tile GEMM body ----------------
// C[row,col] = sum_k A[row,k]*B[col,k]; 256 threads, 4 waves, 32x32/wave.
// BK=64, double-buffered LDS, global_load_lds staging, 1 barrier/K-step.
template <int ADDBIAS>
__device__ __forceinline__ void gemm_tile_lds(
    const __bf16* __restrict__ A, const __bf16* __restrict__ Bm,
    const float* __restrict__ bias, void* __restrict__ C, int as_bf16,
    int row0, int col0, int K, int lda, int ldb, int ldc,
    __bf16* sA, __bf16* sB)   // each 2*4096 elems
{
    int lane = threadIdx.x & 63, wave = threadIdx.x >> 6;
    int wr = wave >> 1, wc = wave & 1;
    int l15 = lane & 15, l4 = lane >> 4;
    int lr = lane >> 3, lc = (lane & 7)*8;   // staging: lane -> (row-in-chunk, col)

    auto stage = [&](int buf, int kt) {
        int k0 = kt*64;
        #pragma unroll
        for (int j = 0; j < 2; ++j) {
            int c = wave*2 + j;          // chunk 0..7, rows [c*8, c*8+8)
            int grow = c*8 + lr;
            gll16(A  + (size_t)(row0+grow)*lda + k0 + lc, sA + buf*4096 + c*512);
            gll16(Bm + (size_t)(col0+grow)*ldb + k0 + lc, sB + buf*4096 + c*512);
        }
    };

    int NT = K >> 6;
    stage(0, 0);
    f32x4 acc[2][2] = {};
    for (int kt = 0; kt < NT; ++kt) {
        int buf = kt & 1;
        asm volatile("s_waitcnt vmcnt(0)");
        __syncthreads();
        if (kt + 1 < NT) stage(buf ^ 1, kt + 1);
        const __bf16* aBase = sA + buf*4096 + (wr*32 + l15)*64 + l4*8;
        const __bf16* bBase = sB + buf*4096 + (wc*32 + l15)*64 + l4*8;
        #pragma unroll
        for (int kk = 0; kk < 2; ++kk) {
            bf16x8 a0 = *(const bf16x8*)(aBase + kk*32);
            bf16x8 a1 = *(const bf16x8*)(aBase + 16*64 + kk*32);
            bf16x8 b0 = *(const bf16x8*)(bBase + kk*32);
            bf16x8 b1 = *(const bf16x8*)(bBase + 16*64 + kk*32);
            acc[0][0] = __builtin_amdgcn_mfma_f32_16x16x32_bf16(a0,b0,acc[0][0],0,0,0);
            acc[0][1] = __builtin_amdgcn_mfma_f32_16x16x32_bf16(a0,b1,acc[0][1],0,0,0);
            acc[1][0] = __builtin_amdgcn_mfma_f32_16x16x32_bf16(a1,b0,acc[1][0],0,0,0);
            acc[1][1] = __builtin_amdgcn_mfma_f32_16x16x32_bf16(a1,b1,acc[1][1],0,0,0);
        }
    }
    int row_a = row0 + wr*32;
    int col_b = col0 + wc*32;
    #pragma unroll
    for (int mi=0; mi<2; mi++)
    #pragma unroll
    for (int ni=0; ni<2; ni++) {
        int r0 = row_a + mi*16 + l4*4;
        int c0 = col_b + ni*16 + l15;
        float bv = ADDBIAS ? bias[c0] : 0.f;
        if (as_bf16) {
            __bf16* Cb = (__bf16*)C;
            #pragma unroll
            for (int r=0; r<4; r++)
                Cb[(size_t)(r0+r)*ldc + c0] = (__bf16)(acc[mi][ni][r] + bv);
        } else {
            float* Cf = (float*)C;
            #pragma unroll
            for (int r=0; r<4; r++)
                Cf[(size_t)(r0+r)*ldc + c0] = acc[mi][ni][r];
        }
    }
}

// XW[m,f] = sum_e Xbf[m,e]*W1x[f,e] + b1[f]; M=32256,N=512,K=512
__global__ __launch_bounds__(256) void k_gemm_xw(
    const __bf16* __restrict__ A, const __bf16* __restrict__ Bm,
    const float* __restrict__ bias, __bf16* __restrict__ C)
{
    __shared__ __bf16 sA[2*4096], sB[2*4096];
    // XCD-chunked bijective swizzle: 4032 blocks = 8 XCDs x 504
    int orig = (blockIdx.x & 7)*504 + (blockIdx.x >> 3);
    int tm = orig >> 3, tn = orig & 7;
    gemm_tile_lds<1>(A, Bm, bias, C, 1, tm*64, tn*64, 512, 512, 512, 512, sA, sB);
}

// blocks 0..63:   dcW [512x512]   = dc[512x1024k] @ Wdc[512n x 1024k]^T
// blocks 64..319: dWhh [512x2048] = d [512x512k]  @ Whh[2048n x 512k]^T  (d = dc rows, lda=1024)
__global__ __launch_bounds__(256) void k_step_gemm(
    const __bf16* __restrict__ dc, const __bf16* __restrict__ Wdc,
    const __bf16* __restrict__ Whh, float* __restrict__ dcW, float* __restrict__ dWhh)
{
    __shared__ __bf16 sA[2*4096], sB[2*4096];
    int blk = blockIdx.x;
    if (blk < 64) {
        int tm = blk >> 3, tn = blk & 7;
        gemm_tile_lds<0>(dc, Wdc, nullptr, dcW, 0, tm*64, tn*64, 1024, 1024, 1024, 512, sA, sB);
    } else {
        int b2 = blk - 64;
        int tm = b2 >> 5, tn = b2 & 31;
        gemm_tile_lds<0>(dc, Whh, nullptr, dWhh, 0, tm*64, tn*64, 512, 1024, 512, 2048, sA, sB);
    }
}

// ---------------- per-step fused kernel ----------------

// one block (512 threads) per batch row
#define PSTR 76   // s_part row stride (floats)
__global__ __launch_bounds__(512) void k_step_fused(
    int t,
    const float* __restrict__ dcW, const float* __restrict__ dWhh,
    const __bf16* __restrict__ XWb, const __bf16* __restrict__ Xbf,
    const float* __restrict__ y_prev, const float* __restrict__ W2,
    const float* __restrict__ fcW, const float* __restrict__ fcb,
    const float* __restrict__ W_ih, const float* __restrict__ bsum,
    float* __restrict__ c_f32, float* __restrict__ d_f32,
    __bf16* __restrict__ dc_bf16, float* __restrict__ ctx_last)
{
    int b = blockIdx.x;
    int tid = threadIdx.x, lane = tid & 63, wave = tid >> 6;
    __shared__ float s_part[64*PSTR];
    __shared__ float s_sc[64];
    __shared__ float s_beta[64];
    __shared__ float s_red[8];
    __shared__ float s_y;

    // hoist per-lane W2 / dcW slices into registers (same f-slice for all 8 t's)
    float w2r[8], dr[8];
    {
        const float4* w2p = (const float4*)(W2 + lane*8);
        const float4* dp  = (const float4*)(dcW + (size_t)b*512 + lane*8);
        float4 w0 = w2p[0], w1 = w2p[1], e0v = dp[0], e1v = dp[1];
        w2r[0]=w0.x; w2r[1]=w0.y; w2r[2]=w0.z; w2r[3]=w0.w;
        w2r[4]=w1.x; w2r[5]=w1.y; w2r[6]=w1.z; w2r[7]=w1.w;
        dr[0]=e0v.x; dr[1]=e0v.y; dr[2]=e0v.z; dr[3]=e0v.w;
        dr[4]=e1v.x; dr[5]=e1v.y; dr[6]=e1v.z; dr[7]=e1v.w;
    }
    // ---- scores: wave w -> t in {w*8..w*8+7}, lane = f-slice (coalesced 1KB/row) ----
    {
        const __bf16* xwp = XWb + ((size_t)b*TM1 + wave*8)*512 + lane*8;
        #pragma unroll
        for (int j = 0; j < 8; ++j) {
            int tt = wave*8 + j;
            float p = 0.f;
            if (tt < TM1) {
                bf16x8 xw = *(const bf16x8*)(xwp + (size_t)j*512);
                #pragma unroll
                for (int i=0;i<8;i++) p += w2r[i]*fast_tanh(dr[i] + (float)xw[i]);
            }
            s_part[tt*PSTR + lane] = p;
        }
    }
    __syncthreads();
    // ---- batched cross-lane reduce: thread -> (tt = tid>>3, g = tid&7) ----
    {
        int tt = tid >> 3, g = tid & 7;
        const float4* pp = (const float4*)(s_part + tt*PSTR + g*8);
        float4 u0 = pp[0], u1 = pp[1];
        float r = u0.x+u0.y+u0.z+u0.w + u1.x+u1.y+u1.z+u1.w;
        r += __shfl_xor(r, 1, 64);
        r += __shfl_xor(r, 2, 64);
        r += __shfl_xor(r, 4, 64);
        if (g == 0) s_sc[tt] = r;
    }
    __syncthreads();
    // ---- softmax over 63 (wave 0); scores bounded by sum|W2| ~ 19 -> exp safe, no max pass
    if (wave == 0) {
        float e = (lane < TM1) ? __expf(s_sc[lane]) : 0.f;
        float sum = e;
        #pragma unroll
        for (int o=32;o;o>>=1) sum += __shfl_xor(sum,o,64);
        s_beta[lane] = e*fast_rcp(sum);   // lane 63 -> 0
    }
    __syncthreads();
    // ---- ctx: thread owns e = tid; 63 coalesced 2B loads (independent) ----
    float ctxv = 0.f;
    {
        const __bf16* xp = Xbf + (size_t)b*TM1*512 + tid;
        #pragma unroll
        for (int tt = 0; tt < TM1; ++tt)
            ctxv += s_beta[tt]*(float)xp[(size_t)tt*512];
    }
    if (t == 62) ctx_last[(size_t)b*512 + tid] = ctxv;
    // ---- y_tilde ----
    float part = fcW[tid]*ctxv;
    #pragma unroll
    for (int o=32;o;o>>=1) part += __shfl_xor(part,o,64);
    if (lane==0) s_red[wave] = part;
    __syncthreads();
    if (tid==0) {
        float y = 0.f;
        #pragma unroll
        for (int w2i=0;w2i<8;w2i++) y += s_red[w2i];
        y += fcW[512]*y_prev[(size_t)b*TM1 + t] + fcb[0];
        s_y = y;
    }
    __syncthreads();
    float yv = s_y;
    // ---- gates + state update: k = tid ----
    {
        int k = tid;
        size_t gb = (size_t)b*2048 + k;
        float gi = dWhh[gb]        + yv*W_ih[k]        + bsum[k];
        float gf = dWhh[gb+512]    + yv*W_ih[512+k]    + bsum[512+k];
        float gg = dWhh[gb+1024]   + yv*W_ih[1024+k]   + bsum[1024+k];
        float go = dWhh[gb+1536]   + yv*W_ih[1536+k]   + bsum[1536+k];
        size_t sk = (size_t)b*512 + k;
        float cn = fast_sigmoid(gf)*c_f32[sk] + fast_sigmoid(gi)*fast_tanh(gg);
        float dn = fast_sigmoid(go)*fast_tanh(cn);
        c_f32[sk] = cn; d_f32[sk] = dn;
        dc_bf16[(size_t)b*1024 + k]       = (__bf16)dn;
        dc_bf16[(size_t)b*1024 + 512 + k] = (__bf16)cn;
    }
}

// final heads: out[0:512]=beta, [512:1024]=sigma, [1024:1536]=gamma
__global__ __launch_bounds__(64) void k_heads(
    const float* __restrict__ d_f32, const float* __restrict__ ctx,
    const float* __restrict__ bW, const float* __restrict__ bb,
    const float* __restrict__ sW, const float* __restrict__ sb,
    const float* __restrict__ gW, const float* __restrict__ gb,
    float* __restrict__ out)
{
    int b = blockIdx.x, lane = threadIdx.x;
    float pb=0.f, ps=0.f, pg=0.f;
    for (int e = lane; e < 1024; e += 64) {
        float v = (e < 512) ? d_f32[(size_t)b*512 + e] : ctx[(size_t)b*512 + e - 512];
        pb += bW[e]*v; ps += sW[e]*v; pg += gW[e]*v;
    }
    #pragma unroll
    for (int o=32;o;o>>=1) {
        pb += __shfl_xor(pb,o,64); ps += __shfl_xor(ps,o,64); pg += __shfl_xor(pg,o,64);
    }
    if (lane==0) {
        out[b]        = pb + bb[0];
        out[512 + b]  = ps + sb[0];
        out[1024 + b] = pg + gb[0];
    }
}

extern "C" void kernel_launch(void* const* d_in, const int* in_sizes, int n_in,
                              void* d_out, int out_size, void* d_ws, size_t ws_size,
                              hipStream_t stream) {
    const float* X      = (const float*)d_in[0];
    const float* y_prev = (const float*)d_in[1];
    const float* W1     = (const float*)d_in[2];
    const float* b1     = (const float*)d_in[3];
    const float* W2     = (const float*)d_in[4];
    // d_in[5] = attn_b2 (softmax-invariant constant shift, skipped)
    const float* fcW    = (const float*)d_in[6];
    const float* fcb    = (const float*)d_in[7];
    const float* W_ih   = (const float*)d_in[8];
    const float* W_hh_f = (const float*)d_in[9];
    const float* b_ih   = (const float*)d_in[10];
    const float* b_hh   = (const float*)d_in[11];
    const float* betaW  = (const float*)d_in[12];
    const float* betab  = (const float*)d_in[13];
    const float* gammaW = (const float*)d_in[14];
    const float* gammab = (const float*)d_in[15];
    const float* sigmaW = (const float*)d_in[16];
    const float* sigmab = (const float*)d_in[17];
    float* out = (float*)d_out;

    size_t off = 0;
    char* ws = (char*)d_ws;
    auto alloc = [&](size_t bytes) { void* p = ws + off; off += (bytes + 255) & ~(size_t)255; return p; };
    __bf16* XWb  = (__bf16*)alloc((size_t)Bn*TM1*512*2);
    __bf16* Xbf  = (__bf16*)alloc((size_t)Bn*TM1*512*2);
    __bf16* Wdc  = (__bf16*)alloc((size_t)512*1024*2);
    __bf16* W1x  = (__bf16*)alloc((size_t)512*512*2);
    __bf16* Whh  = (__bf16*)alloc((size_t)2048*512*2);
    __bf16* dcb  = (__bf16*)alloc((size_t)Bn*1024*2);
    float*  cf   = (float*)alloc((size_t)Bn*512*4);
    float*  df   = (float*)alloc((size_t)Bn*512*4);
    float*  dcW  = (float*)alloc((size_t)Bn*512*4);
    float*  dWhh = (float*)alloc((size_t)Bn*2048*4);
    float*  ctxl = (float*)alloc((size_t)Bn*512*4);
    float*  bsum = (float*)alloc((size_t)2048*4);

    hipMemsetAsync(dcb, 0, (size_t)Bn*1024*2, stream);
    hipMemsetAsync(cf,  0, (size_t)Bn*512*4, stream);

    k_prep_weights<<<512, 256, 0, stream>>>(W1, W_hh_f, b_ih, b_hh, Wdc, W1x, Whh, bsum);
    int nx = Bn*TM1*512;
    k_conv_x<<<(nx/4 + 255)/256, 256, 0, stream>>>(X, Xbf, nx);
    k_gemm_xw<<<(Bn*TM1/64)*8, 256, 0, stream>>>(Xbf, W1x, b1, XWb);

    for (int t = 0; t < TM1; ++t) {
        k_step_gemm<<<320, 256, 0, stream>>>(dcb, Wdc, Whh, dcW, dWhh);
        k_step_fused<<<Bn, 512, 0, stream>>>(t, dcW, dWhh, XWb, Xbf, y_prev, W2,
                                             fcW, fcb, W_ih, bsum,
                                             cf, df, dcb, ctxl);
    }
    k_heads<<<Bn, 64, 0, stream>>>(df, ctxl, betaW, betab, sigmaW, sigmab, gammaW, gammab, out);
}

// Round 6
// 1666.712 us; speedup vs baseline: 2.1747x; 1.2063x over previous
//
#include <hip/hip_runtime.h>

typedef __bf16 bf16x8 __attribute__((ext_vector_type(8)));
typedef float  f32x4  __attribute__((ext_vector_type(4)));

#define Bn  512
#define TM1 63

__device__ __forceinline__ float fast_rcp(float x){ return __builtin_amdgcn_rcpf(x); }
__device__ __forceinline__ float fast_tanh(float x){
    float e = __expf(2.0f*x);
    return 1.0f - 2.0f*fast_rcp(e + 1.0f);
}
__device__ __forceinline__ float fast_sigmoid(float x){
    return fast_rcp(1.0f + __expf(-x));
}

// async global->LDS, 16B per lane; lds ptr must be wave-uniform (HW adds lane*16)
__device__ __forceinline__ void gll16(const __bf16* g, __bf16* l) {
    __builtin_amdgcn_global_load_lds(
        (const __attribute__((address_space(1))) unsigned int*)(g),
        (__attribute__((address_space(3))) unsigned int*)(l),
        16, 0, 0);
}

// ---------------- setup kernels ----------------

__global__ __launch_bounds__(256) void k_prep_weights(
    const float* __restrict__ W1, const float* __restrict__ Whh_f,
    const float* __restrict__ b_ih, const float* __restrict__ b_hh,
    __bf16* __restrict__ Wdc, __bf16* __restrict__ W1x, __bf16* __restrict__ Whh,
    float* __restrict__ bsum)
{
    int i = blockIdx.x*256 + threadIdx.x;
    int n = gridDim.x*256;
    for (int idx = i; idx < 512*1024; idx += n) {
        int f = idx >> 10, k = idx & 1023;
        Wdc[idx] = (__bf16)W1[f*1536 + k];
    }
    for (int idx = i; idx < 512*512; idx += n) {
        int f = idx >> 9, k = idx & 511;
        W1x[idx] = (__bf16)W1[f*1536 + 1024 + k];
    }
    for (int idx = i; idx < 2048*512; idx += n) {
        Whh[idx] = (__bf16)Whh_f[idx];
    }
    for (int idx = i; idx < 2048; idx += n) {
        bsum[idx] = b_ih[idx] + b_hh[idx];
    }
}

__global__ __launch_bounds__(256) void k_conv_x(const float* __restrict__ X, __bf16* __restrict__ Xb, int n)
{
    int idx = (blockIdx.x*256 + threadIdx.x)*4;
    if (idx < n) {
        float4 v = *(const float4*)(X + idx);
        Xb[idx+0] = (__bf16)v.x; Xb[idx+1] = (__bf16)v.y;
        Xb[idx+2] = (__bf16)v.z; Xb[idx+3] = (__bf16)v.w;
    }
}

// XF[m] = sum_e Xbf[m,e]*fcW[e]  for m in [0, Bn*TM1); wave-per-row, 8 rows/wave
__global__ __launch_bounds__(256) void k_xf(
    const __bf16* __restrict__ Xbf, const float* __restrict__ fcW, float* __restrict__ XF)
{
    int lane = threadIdx.x & 63, wave = threadIdx.x >> 6;
    float fcr[8];
    {
        const float4* fp = (const float4*)(fcW + lane*8);
        float4 f0 = fp[0], f1 = fp[1];
        fcr[0]=f0.x; fcr[1]=f0.y; fcr[2]=f0.z; fcr[3]=f0.w;
        fcr[4]=f1.x; fcr[5]=f1.y; fcr[6]=f1.z; fcr[7]=f1.w;
    }
    int row0 = (blockIdx.x*4 + wave)*8;
    #pragma unroll
    for (int j = 0; j < 8; ++j) {
        int row = row0 + j;
        if (row >= Bn*TM1) break;
        bf16x8 x = *(const bf16x8*)(Xbf + (size_t)row*512 + lane*8);
        float p = 0.f;
        #pragma unroll
        for (int i=0;i<8;i++) p += fcr[i]*(float)x[i];
        #pragma unroll
        for (int o=32;o;o>>=1) p += __shfl_xor(p,o,64);
        if (lane==0) XF[row] = p;
    }
}

// ---------------- LDS-staged 64x64-tile GEMM body (XOR-swizzled) ----------------
// C[row,col] = sum_k A[row,k]*B[col,k]; 256 threads, 4 waves, 32x32/wave.
// BK=64, double-buffered LDS, global_load_lds staging, 1 barrier/K-step.
// Swizzle (both sides, rule #21): LDS 16B-chunk j of row r holds global chunk j^(r&7).
template <int ADDBIAS>
__device__ __forceinline__ void gemm_tile_lds(
    const __bf16* __restrict__ A, const __bf16* __restrict__ Bm,
    const float* __restrict__ bias, void* __restrict__ C, int as_bf16,
    int row0, int col0, int K, int lda, int ldb, int ldc,
    __bf16* sA, __bf16* sB)   // each 2*4096 elems
{
    int lane = threadIdx.x & 63, wave = threadIdx.x >> 6;
    int wr = wave >> 1, wc = wave & 1;
    int l15 = lane & 15, l4 = lane >> 4;
    int lr = lane >> 3;                      // row-in-chunk 0..7
    int lcs = ((lane & 7) ^ lr) * 8;         // inverse-swizzled source column (elements)

    auto stage = [&](int buf, int kt) {
        int k0 = kt*64;
        #pragma unroll
        for (int j = 0; j < 2; ++j) {
            int c = wave*2 + j;          // chunk 0..7, rows [c*8, c*8+8)
            int grow = c*8 + lr;
            gll16(A  + (size_t)(row0+grow)*lda + k0 + lcs, sA + buf*4096 + c*512);
            gll16(Bm + (size_t)(col0+grow)*ldb + k0 + lcs, sB + buf*4096 + c*512);
        }
    };

    int NT = K >> 6;
    stage(0, 0);
    f32x4 acc[2][2] = {};
    int s7 = l15 & 7;
    const __bf16* aRow = sA + (wr*32 + l15)*64;
    const __bf16* bRow = sB + (wc*32 + l15)*64;
    for (int kt = 0; kt < NT; ++kt) {
        int buf = kt & 1;
        asm volatile("s_waitcnt vmcnt(0)");
        __syncthreads();
        if (kt + 1 < NT) stage(buf ^ 1, kt + 1);
        #pragma unroll
        for (int kk = 0; kk < 2; ++kk) {
            int ch = ((l4 + kk*4) ^ s7) * 8;
            bf16x8 a0 = *(const bf16x8*)(aRow + buf*4096 + ch);
            bf16x8 a1 = *(const bf16x8*)(aRow + buf*4096 + 16*64 + ch);
            bf16x8 b0 = *(const bf16x8*)(bRow + buf*4096 + ch);
            bf16x8 b1 = *(const bf16x8*)(bRow + buf*4096 + 16*64 + ch);
            acc[0][0] = __builtin_amdgcn_mfma_f32_16x16x32_bf16(a0,b0,acc[0][0],0,0,0);
            acc[0][1] = __builtin_amdgcn_mfma_f32_16x16x32_bf16(a0,b1,acc[0][1],0,0,0);
            acc[1][0] = __builtin_amdgcn_mfma_f32_16x16x32_bf16(a1,b0,acc[1][0],0,0,0);
            acc[1][1] = __builtin_amdgcn_mfma_f32_16x16x32_bf16(a1,b1,acc[1][1],0,0,0);
        }
    }
    int row_a = row0 + wr*32;
    int col_b = col0 + wc*32;
    #pragma unroll
    for (int mi=0; mi<2; mi++)
    #pragma unroll
    for (int ni=0; ni<2; ni++) {
        int r0 = row_a + mi*16 + l4*4;
        int c0 = col_b + ni*16 + l15;
        float bv = ADDBIAS ? bias[c0] : 0.f;
        if (as_bf16) {
            __bf16* Cb = (__bf16*)C;
            #pragma unroll
            for (int r=0; r<4; r++)
                Cb[(size_t)(r0+r)*ldc + c0] = (__bf16)(acc[mi][ni][r] + bv);
        } else {
            float* Cf = (float*)C;
            #pragma unroll
            for (int r=0; r<4; r++)
                Cf[(size_t)(r0+r)*ldc + c0] = acc[mi][ni][r];
        }
    }
}

// XW[m,f] = sum_e Xbf[m,e]*W1x[f,e] + b1[f]; M=32256,N=512,K=512
__global__ __launch_bounds__(256) void k_gemm_xw(
    const __bf16* __restrict__ A, const __bf16* __restrict__ Bm,
    const float* __restrict__ bias, __bf16* __restrict__ C)
{
    __shared__ __bf16 sA[2*4096], sB[2*4096];
    // XCD-chunked bijective swizzle: 4032 blocks = 8 XCDs x 504
    int orig = (blockIdx.x & 7)*504 + (blockIdx.x >> 3);
    int tm = orig >> 3, tn = orig & 7;
    gemm_tile_lds<1>(A, Bm, bias, C, 1, tm*64, tn*64, 512, 512, 512, 512, sA, sB);
}

// blocks 0..63:   dcW [512x512]   = dc[512x1024k] @ Wdc[512n x 1024k]^T
// blocks 64..319: dWhh [512x2048] = d [512x512k]  @ Whh[2048n x 512k]^T  (d = dc rows, lda=1024)
__global__ __launch_bounds__(256) void k_step_gemm(
    const __bf16* __restrict__ dc, const __bf16* __restrict__ Wdc,
    const __bf16* __restrict__ Whh, float* __restrict__ dcW, float* __restrict__ dWhh)
{
    __shared__ __bf16 sA[2*4096], sB[2*4096];
    int blk = blockIdx.x;
    if (blk < 64) {
        int tm = blk >> 3, tn = blk & 7;
        gemm_tile_lds<0>(dc, Wdc, nullptr, dcW, 0, tm*64, tn*64, 1024, 1024, 1024, 512, sA, sB);
    } else {
        int b2 = blk - 64;
        int tm = b2 >> 5, tn = b2 & 31;
        gemm_tile_lds<0>(dc, Whh, nullptr, dWhh, 0, tm*64, tn*64, 512, 1024, 512, 2048, sA, sB);
    }
}

// ---------------- per-step fused kernel ----------------

// one block (512 threads) per batch row; no ctx phase (XF trick)
#define PSTR 76   // s_part row stride (floats)
__global__ __launch_bounds__(512) void k_step_fused(
    int t,
    const float* __restrict__ dcW, const float* __restrict__ dWhh,
    const __bf16* __restrict__ XWb, const float* __restrict__ XF,
    const float* __restrict__ y_prev, const float* __restrict__ W2,
    const float* __restrict__ fcW, const float* __restrict__ fcb,
    const float* __restrict__ W_ih, const float* __restrict__ bsum,
    float* __restrict__ c_f32, float* __restrict__ d_f32,
    __bf16* __restrict__ dc_bf16, float* __restrict__ beta_out)
{
    int b = blockIdx.x;
    int tid = threadIdx.x, lane = tid & 63, wave = tid >> 6;
    __shared__ float s_part[64*PSTR];
    __shared__ float s_sc[64];
    __shared__ float s_y;

    // hoist per-lane W2 / dcW slices into registers (same f-slice for all 8 t's)
    float w2r[8], dr[8];
    {
        const float4* w2p = (const float4*)(W2 + lane*8);
        const float4* dp  = (const float4*)(dcW + (size_t)b*512 + lane*8);
        float4 w0 = w2p[0], w1 = w2p[1], e0v = dp[0], e1v = dp[1];
        w2r[0]=w0.x; w2r[1]=w0.y; w2r[2]=w0.z; w2r[3]=w0.w;
        w2r[4]=w1.x; w2r[5]=w1.y; w2r[6]=w1.z; w2r[7]=w1.w;
        dr[0]=e0v.x; dr[1]=e0v.y; dr[2]=e0v.z; dr[3]=e0v.w;
        dr[4]=e1v.x; dr[5]=e1v.y; dr[6]=e1v.z; dr[7]=e1v.w;
    }
    // ---- scores: wave w -> t in {w*8..w*8+7}, lane = f-slice (coalesced 1KB/row) ----
    {
        const __bf16* xwp = XWb + ((size_t)b*TM1 + wave*8)*512 + lane*8;
        #pragma unroll
        for (int j = 0; j < 8; ++j) {
            int tt = wave*8 + j;
            float p = 0.f;
            if (tt < TM1) {
                bf16x8 xw = *(const bf16x8*)(xwp + (size_t)j*512);
                #pragma unroll
                for (int i=0;i<8;i++) p += w2r[i]*fast_tanh(dr[i] + (float)xw[i]);
            }
            s_part[tt*PSTR + lane] = p;
        }
    }
    __syncthreads();
    // ---- batched cross-lane reduce: thread -> (tt = tid>>3, g = tid&7) ----
    {
        int tt = tid >> 3, g = tid & 7;
        const float4* pp = (const float4*)(s_part + tt*PSTR + g*8);
        float4 u0 = pp[0], u1 = pp[1];
        float r = u0.x+u0.y+u0.z+u0.w + u1.x+u1.y+u1.z+u1.w;
        r += __shfl_xor(r, 1, 64);
        r += __shfl_xor(r, 2, 64);
        r += __shfl_xor(r, 4, 64);
        if (g == 0) s_sc[tt] = r;
    }
    __syncthreads();
    // ---- softmax over 63 + y via XF dot (wave 0); no max pass (|s| <= sum|W2| ~ 19) ----
    if (wave == 0) {
        float e = (lane < TM1) ? __expf(s_sc[lane]) : 0.f;
        float sum = e;
        #pragma unroll
        for (int o=32;o;o>>=1) sum += __shfl_xor(sum,o,64);
        float beta = e*fast_rcp(sum);      // lane 63 -> 0
        if (t == 62) beta_out[b*64 + lane] = beta;
        float yp = (lane < TM1) ? beta*XF[(size_t)b*TM1 + lane] : 0.f;
        #pragma unroll
        for (int o=32;o;o>>=1) yp += __shfl_xor(yp,o,64);
        if (lane == 0)
            s_y = yp + fcW[512]*y_prev[(size_t)b*TM1 + t] + fcb[0];
    }
    __syncthreads();
    float yv = s_y;
    // ---- gates + state update: k = tid ----
    {
        int k = tid;
        size_t gb = (size_t)b*2048 + k;
        float gi = dWhh[gb]        + yv*W_ih[k]        + bsum[k];
        float gf = dWhh[gb+512]    + yv*W_ih[512+k]    + bsum[512+k];
        float gg = dWhh[gb+1024]   + yv*W_ih[1024+k]   + bsum[1024+k];
        float go = dWhh[gb+1536]   + yv*W_ih[1536+k]   + bsum[1536+k];
        size_t sk = (size_t)b*512 + k;
        float cn = fast_sigmoid(gf)*c_f32[sk] + fast_sigmoid(gi)*fast_tanh(gg);
        float dn = fast_sigmoid(go)*fast_tanh(cn);
        c_f32[sk] = cn; d_f32[sk] = dn;
        dc_bf16[(size_t)b*1024 + k]       = (__bf16)dn;
        dc_bf16[(size_t)b*1024 + 512 + k] = (__bf16)cn;
    }
}

// ---------------- finish: ctx_last from beta(62) + heads ----------------
// out[0:512]=beta, [512:1024]=sigma, [1024:1536]=gamma
__global__ __launch_bounds__(512) void k_finish(
    const float* __restrict__ beta62, const __bf16* __restrict__ Xbf,
    const float* __restrict__ d_f32,
    const float* __restrict__ bW, const float* __restrict__ bb,
    const float* __restrict__ sW, const float* __restrict__ sb,
    const float* __restrict__ gW, const float* __restrict__ gb,
    float* __restrict__ out)
{
    int b = blockIdx.x;
    int tid = threadIdx.x, lane = tid & 63, wave = tid >> 6;
    __shared__ float s_beta[64];
    __shared__ float s_red[3][8];
    if (tid < 64) s_beta[tid] = beta62[b*64 + tid];
    __syncthreads();
    // ctx[e=tid] = sum_t beta[t] X[b,t,e]  (coalesced 2B loads, 63 independent)
    float ctxv = 0.f;
    {
        const __bf16* xp = Xbf + (size_t)b*TM1*512 + tid;
        #pragma unroll
        for (int tt = 0; tt < TM1; ++tt)
            ctxv += s_beta[tt]*(float)xp[(size_t)tt*512];
    }
    float dv = d_f32[(size_t)b*512 + tid];
    float pb = bW[tid]*dv + bW[512+tid]*ctxv;
    float ps = sW[tid]*dv + sW[512+tid]*ctxv;
    float pg = gW[tid]*dv + gW[512+tid]*ctxv;
    #pragma unroll
    for (int o=32;o;o>>=1) {
        pb += __shfl_xor(pb,o,64); ps += __shfl_xor(ps,o,64); pg += __shfl_xor(pg,o,64);
    }
    if (lane==0) { s_red[0][wave]=pb; s_red[1][wave]=ps; s_red[2][wave]=pg; }
    __syncthreads();
    if (tid==0) {
        float sb_=0,ss_=0,sg_=0;
        #pragma unroll
        for (int w=0;w<8;w++){ sb_+=s_red[0][w]; ss_+=s_red[1][w]; sg_+=s_red[2][w]; }
        out[b]        = sb_ + bb[0];
        out[512 + b]  = ss_ + sb[0];
        out[1024 + b] = sg_ + gb[0];
    }
}

extern "C" void kernel_launch(void* const* d_in, const int* in_sizes, int n_in,
                              void* d_out, int out_size, void* d_ws, size_t ws_size,
                              hipStream_t stream) {
    const float* X      = (const float*)d_in[0];
    const float* y_prev = (const float*)d_in[1];
    const float* W1     = (const float*)d_in[2];
    const float* b1     = (const float*)d_in[3];
    const float* W2     = (const float*)d_in[4];
    // d_in[5] = attn_b2 (softmax-invariant constant shift, skipped)
    const float* fcW    = (const float*)d_in[6];
    const float* fcb    = (const float*)d_in[7];
    const float* W_ih   = (const float*)d_in[8];
    const float* W_hh_f = (const float*)d_in[9];
    const float* b_ih   = (const float*)d_in[10];
    const float* b_hh   = (const float*)d_in[11];
    const float* betaW  = (const float*)d_in[12];
    const float* betab  = (const float*)d_in[13];
    const float* gammaW = (const float*)d_in[14];
    const float* gammab = (const float*)d_in[15];
    const float* sigmaW = (const float*)d_in[16];
    const float* sigmab = (const float*)d_in[17];
    float* out = (float*)d_out;

    size_t off = 0;
    char* ws = (char*)d_ws;
    auto alloc = [&](size_t bytes) { void* p = ws + off; off += (bytes + 255) & ~(size_t)255; return p; };
    __bf16* XWb  = (__bf16*)alloc((size_t)Bn*TM1*512*2);
    __bf16* Xbf  = (__bf16*)alloc((size_t)Bn*TM1*512*2);
    __bf16* Wdc  = (__bf16*)alloc((size_t)512*1024*2);
    __bf16* W1x  = (__bf16*)alloc((size_t)512*512*2);
    __bf16* Whh  = (__bf16*)alloc((size_t)2048*512*2);
    __bf16* dcb  = (__bf16*)alloc((size_t)Bn*1024*2);
    float*  cf   = (float*)alloc((size_t)Bn*512*4);
    float*  df   = (float*)alloc((size_t)Bn*512*4);
    float*  dcW  = (float*)alloc((size_t)Bn*512*4);
    float*  dWhh = (float*)alloc((size_t)Bn*2048*4);
    float*  bsum = (float*)alloc((size_t)2048*4);
    float*  XF   = (float*)alloc((size_t)Bn*TM1*4);
    float*  b62  = (float*)alloc((size_t)Bn*64*4);

    hipMemsetAsync(dcb, 0, (size_t)Bn*1024*2, stream);
    hipMemsetAsync(cf,  0, (size_t)Bn*512*4, stream);

    k_prep_weights<<<512, 256, 0, stream>>>(W1, W_hh_f, b_ih, b_hh, Wdc, W1x, Whh, bsum);
    int nx = Bn*TM1*512;
    k_conv_x<<<(nx/4 + 255)/256, 256, 0, stream>>>(X, Xbf, nx);
    k_xf<<<(Bn*TM1 + 31)/32, 256, 0, stream>>>(Xbf, fcW, XF);
    k_gemm_xw<<<(Bn*TM1/64)*8, 256, 0, stream>>>(Xbf, W1x, b1, XWb);

    for (int t = 0; t < TM1; ++t) {
        k_step_gemm<<<320, 256, 0, stream>>>(dcb, Wdc, Whh, dcW, dWhh);
        k_step_fused<<<Bn, 512, 0, stream>>>(t, dcW, dWhh, XWb, XF, y_prev, W2,
                                             fcW, fcb, W_ih, bsum,
                                             cf, df, dcb, b62);
    }
    k_finish<<<Bn, 512, 0, stream>>>(b62, Xbf, df,
                                     betaW, betab, sigmaW, sigmab, gammaW, gammab, out);
}